// Round 4
// baseline (241.349 us; speedup 1.0000x reference)
//
#include <hip/hip_runtime.h>
#include <hip/hip_cooperative_groups.h>
#include <math.h>

namespace cg = cooperative_groups;

// ---------------- problem constants ----------------
#define BATCH   16
#define T_LEN   262144
#define NB      16          // biquad stages
#define L       64          // samples per chunk
#define GRP     64          // chunks per group (== wave width)
#define SUB     16          // chunks per sub-group
#define NSUP    16          // super-groups per batch

#define DPI 3.14159265358979323846264338327950288

// ---------------- ws layout (floats) ----------------
#define OFF_COEF  0          // [16][96]
#define OFF_A64   1536       // [16][32][32]  A^64    (f32, f64-computed)
#define OFF_A1K   17920      // [16][32][32]  A^1024
#define OFF_A16K  34304      // [16][32][32]  A^16384
#define OFF_QSUP  50688      // [16][16][32]  super totals
#define OFF_SSUP  58880      // [16][16][32]  super start states
// total 67072 floats ~= 268 KB

// ---------------- stage coefficient math (f64) ----------------
__device__ inline void stage_coefs(int i, double fn, double gn, double qn,
                                   double& B0, double& B1, double& B2,
                                   double& A1, double& A2) {
    const double FS = 96000.0;
    double Q    = exp(log(0.5) + qn * (log(16.0) - log(0.5)));
    double gain = -24.0 + gn * 48.0;
    double lo, hi;
    if (i == 0)            { lo = 20.0;   hi = 500.0;   }
    else if (i == 15)      { lo = 5000.0; hi = 20000.0; }
    else if (i == 1 || i == 14) { lo = 50.0; hi = 16000.0; }
    else                   { lo = 100.0;  hi = 15000.0; }
    double fc    = exp(log(lo) + fn * (log(hi) - log(lo)));
    double w0    = 2.0 * DPI * fc / FS;
    double alpha = sin(w0) / (2.0 * Q);
    double c     = cos(w0);
    double b0, b1, b2, a0, a1, a2;
    if (i == 0) {
        b0 = (1.0 + c) * 0.5; b1 = -(1.0 + c); b2 = (1.0 + c) * 0.5;
        a0 = 1.0 + alpha; a1 = -2.0 * c; a2 = 1.0 - alpha;
    } else if (i == 15) {
        b0 = (1.0 - c) * 0.5; b1 = 1.0 - c; b2 = (1.0 - c) * 0.5;
        a0 = 1.0 + alpha; a1 = -2.0 * c; a2 = 1.0 - alpha;
    } else if (i == 1) {
        double A = pow(10.0, gain / 40.0), sA = sqrt(A);
        b0 = A * ((A + 1.0) - (A - 1.0) * c + 2.0 * sA * alpha);
        b1 = 2.0 * A * ((A - 1.0) - (A + 1.0) * c);
        b2 = A * ((A + 1.0) - (A - 1.0) * c - 2.0 * sA * alpha);
        a0 = (A + 1.0) + (A - 1.0) * c + 2.0 * sA * alpha;
        a1 = -2.0 * ((A - 1.0) + (A + 1.0) * c);
        a2 = (A + 1.0) + (A - 1.0) * c - 2.0 * sA * alpha;
    } else if (i == 14) {
        double A = pow(10.0, gain / 40.0), sA = sqrt(A);
        b0 = A * ((A + 1.0) + (A - 1.0) * c + 2.0 * sA * alpha);
        b1 = -2.0 * A * ((A - 1.0) + (A + 1.0) * c);
        b2 = A * ((A + 1.0) + (A - 1.0) * c - 2.0 * sA * alpha);
        a0 = (A + 1.0) - (A - 1.0) * c + 2.0 * sA * alpha;
        a1 = 2.0 * ((A - 1.0) - (A + 1.0) * c);
        a2 = (A + 1.0) - (A - 1.0) * c - 2.0 * sA * alpha;
    } else {
        double A = pow(10.0, gain / 40.0);
        b0 = 1.0 + alpha * A; b1 = -2.0 * c; b2 = 1.0 - alpha * A;
        a0 = 1.0 + alpha / A; a1 = -2.0 * c; a2 = 1.0 - alpha / A;
    }
    B0 = b0 / a0; B1 = b1 / a0; B2 = b2 / a0; A1 = a1 / a0; A2 = a2 / a0;
}

// ---------------- K0: coefs + A^64 / A^1024 / A^16384 (f64) -----------------
// f64 REQUIRED: intermediate powers of the non-normal cascade matrix
// transiently exceed f32 range (f32 chain -> Inf -> NaN).
__global__ __launch_bounds__(256) void k0_setup(const float* __restrict__ params,
                                                float* __restrict__ coefs,
                                                float* __restrict__ A64,
                                                float* __restrict__ A1K,
                                                float* __restrict__ A16K) {
    int b = blockIdx.x;
    int t = threadIdx.x;
    __shared__ double cf[NB][5];
    __shared__ double M1[32 * 32];
    __shared__ double M2[32 * 32];

    if (t < NB) {
        double B0, B1, B2, A1, A2;
        stage_coefs(t, (double)params[b * 50 + t * 3 + 0],
                       (double)params[b * 50 + t * 3 + 1],
                       (double)params[b * 50 + t * 3 + 2], B0, B1, B2, A1, A2);
        float f0 = (float)B0, f1 = (float)B1, f2 = (float)B2, f3 = (float)A1, f4 = (float)A2;
        cf[t][0] = (double)f0; cf[t][1] = (double)f1; cf[t][2] = (double)f2;
        cf[t][3] = (double)f3; cf[t][4] = (double)f4;
        float* cp = coefs + b * 96 + t * 5;
        cp[0] = f0; cp[1] = f1; cp[2] = f2; cp[3] = f3; cp[4] = f4;
    }
    if (t == NB) {
        double indb = -60.0 + (double)params[b * 50 + 48] * 60.0;
        coefs[b * 96 + 80] = (float)pow(10.0, indb / 20.0);
    }
    if (t == NB + 1) {
        double outdb = -60.0 + (double)params[b * 50 + 49] * 60.0;
        coefs[b * 96 + 81] = (float)pow(10.0, outdb / 20.0);
    }
    __syncthreads();

    if (t < 32) {
        double s1[NB], s2[NB];
#pragma unroll
        for (int i = 0; i < NB; i++) {
            s1[i] = (t == 2 * i) ? 1.0 : 0.0;
            s2[i] = (t == 2 * i + 1) ? 1.0 : 0.0;
        }
        double u = 0.0;
#pragma unroll
        for (int i = 0; i < NB; i++) {
            double y  = cf[i][0] * u + s1[i];
            double n1 = cf[i][1] * u - cf[i][3] * y + s2[i];
            double n2 = cf[i][2] * u - cf[i][4] * y;
            s1[i] = n1; s2[i] = n2; u = y;
        }
#pragma unroll
        for (int i = 0; i < NB; i++) {
            M1[(2 * i) * 32 + t]     = s1[i];
            M1[(2 * i + 1) * 32 + t] = s2[i];
        }
    }
    __syncthreads();

    // 14 squarings; save A^64 (sq=5), A^1024 (sq=9), A^16384 (sq=13).
    int c  = t & 31;
    int r0 = t >> 5;
    double* src = M1;
    double* dst = M2;
    for (int sq = 0; sq < 14; sq++) {
        double acc[4] = {0.0, 0.0, 0.0, 0.0};
        for (int k = 0; k < 32; k++) {
            double bv = src[k * 32 + c];
#pragma unroll
            for (int e = 0; e < 4; e++)
                acc[e] += src[(e * 8 + r0) * 32 + k] * bv;
        }
#pragma unroll
        for (int e = 0; e < 4; e++) dst[(e * 8 + r0) * 32 + c] = acc[e];
        __syncthreads();
        { double* tmp = src; src = dst; dst = tmp; }
        float* out_m = (sq == 5) ? A64 : (sq == 9) ? A1K : (sq == 13) ? A16K : nullptr;
        if (out_m) {
#pragma unroll
            for (int e = 0; e < 4; e++) {
                int idx = (e * 8 + r0) * 32 + c;
                out_m[b * 1024 + idx] = (float)src[idx];
            }
        }
        __syncthreads();
    }
}

// ---------------- readlane matvec step (grouped broadcasts) -----------------
__device__ __forceinline__ float mv_step_rl(const float* ar, float q, float addv) {
    int qi = __float_as_int(q);
    float qb[32];
#pragma unroll
    for (int t = 0; t < 32; t++)
        qb[t] = __int_as_float(__builtin_amdgcn_readlane(qi, t));
    float acc0 = addv, acc1 = 0.f;
#pragma unroll
    for (int t = 0; t < 32; t += 2) {
        acc0 = fmaf(ar[t], qb[t], acc0);
        acc1 = fmaf(ar[t + 1], qb[t + 1], acc1);
    }
    return acc0 + acc1;
}

__device__ __forceinline__ void load_row32(const float* base, int row, float* ar) {
    const float4* a4 = (const float4*)(base + row * 32);
#pragma unroll
    for (int j = 0; j < 8; j++) {
        float4 v = a4[j];
        ar[4 * j + 0] = v.x; ar[4 * j + 1] = v.y;
        ar[4 * j + 2] = v.z; ar[4 * j + 3] = v.w;
    }
}

// 4-sample biquad cascade step. Fully inlined/unrolled -> arrays stay in regs
// (coefs are wave-uniform loads -> SGPRs).
__device__ __forceinline__ void biquad4(const float4& xc, float ing,
                                        const float* c0, const float* c1,
                                        const float* c2, const float* c3,
                                        const float* c4,
                                        float* s1, float* s2, float* ys) {
    float xs[4] = {xc.x, xc.y, xc.z, xc.w};
#pragma unroll
    for (int j = 0; j < 4; j++) {
        float u = ing * xs[j];
#pragma unroll
        for (int i = 0; i < NB; i++) {
            float y  = fmaf(c0[i], u, s1[i]);
            float n1 = fmaf(c1[i], u, s2[i]); n1 = fmaf(-c3[i], y, n1);
            float n2 = c2[i] * u;             n2 = fmaf(-c4[i], y, n2);
            s1[i] = n1; s2[i] = n2; u = y;
        }
        ys[j] = u;
    }
}

// ---- KF: fused pass1 + combine + pass2, single cooperative launch. ----
// 256 blocks x 256 threads = 1024 waves (1 block/CU, co-resident).
// Block b = (batch b>>4, super b&15) owns groups sup*4..sup*4+3 (1/wave),
// subs sup*16..sup*16+15, super sup. P and sub-totals never leave LDS;
// only super-level state (32 KB total) crosses blocks, around 2 grid syncs.
__global__ __launch_bounds__(256, 1) void kfused(const float* __restrict__ audio,
                                                 const float* __restrict__ coefs,
                                                 const float* __restrict__ A64,
                                                 const float* __restrict__ A1K,
                                                 const float* __restrict__ A16K,
                                                 float* __restrict__ qsupg,
                                                 float* __restrict__ ssupg,
                                                 float* __restrict__ out) {
    cg::grid_group grid = cg::this_grid();
    int tid   = threadIdx.x;
    int w     = tid >> 6;        // wave 0..3 = group within super
    int lane  = tid & 63;
    int row   = lane & 31;
    int batch = blockIdx.x >> 4;
    int sup   = blockIdx.x & 15;
    int grp   = sup * 4 + w;     // group 0..63 within batch

    __shared__ float plds[4][GRP][33];   // chunk states per wave, 33.8 KB
    __shared__ float qend_l[16][32];     // block's 16 sub totals
    __shared__ float ssub_l[16][32];     // seeded sub start states

    const float* cf = coefs + batch * 96;
    float c0[NB], c1[NB], c2[NB], c3[NB], c4[NB];
#pragma unroll
    for (int i = 0; i < NB; i++) {
        c0[i] = cf[i * 5 + 0]; c1[i] = cf[i * 5 + 1]; c2[i] = cf[i * 5 + 2];
        c3[i] = cf[i * 5 + 3]; c4[i] = cf[i * 5 + 4];
    }
    float ing  = cf[80];
    float outg = cf[81];

    // ---------- phase 1: zero-init biquad pass ----------
    float s1[NB], s2[NB];
#pragma unroll
    for (int i = 0; i < NB; i++) { s1[i] = 0.f; s2[i] = 0.f; }

    const float4* xgv = (const float4*)(audio + (size_t)batch * T_LEN
                                        + ((size_t)grp * GRP + lane) * L);
    float ys[4];
    {
        float4 xv = xgv[0];
#pragma unroll 1
        for (int tt = 0; tt < 15; tt++) {
            float4 xc = xv;
            xv = xgv[tt + 1];
            biquad4(xc, ing, c0, c1, c2, c3, c4, s1, s2, ys);
        }
        biquad4(xv, ing, c0, c1, c2, c3, c4, s1, s2, ys);
    }
#pragma unroll
    for (int i = 0; i < NB; i++) {
        plds[w][lane][2 * i]     = s1[i];
        plds[w][lane][2 * i + 1] = s2[i];
    }
    __syncthreads();

    // ---------- sub-group totals (4 chains per wave, A^64) ----------
    {
        float ar[32];
        load_row32(A64 + batch * 1024, row, ar);
        float q0 = 0.f, q1 = 0.f, q2 = 0.f, q3 = 0.f;
#pragma unroll 1
        for (int j = 0; j < SUB; j++) {
            float p0 = plds[w][0 * SUB + j][row];
            float p1 = plds[w][1 * SUB + j][row];
            float p2 = plds[w][2 * SUB + j][row];
            float p3 = plds[w][3 * SUB + j][row];
            q0 = mv_step_rl(ar, q0, p0);
            q1 = mv_step_rl(ar, q1, p1);
            q2 = mv_step_rl(ar, q2, p2);
            q3 = mv_step_rl(ar, q3, p3);
        }
        if (lane < 32) {
            qend_l[w * 4 + 0][row] = q0;
            qend_l[w * 4 + 1][row] = q1;
            qend_l[w * 4 + 2][row] = q2;
            qend_l[w * 4 + 3][row] = q3;
        }
    }
    __syncthreads();

    // ---------- super total (wave 0, A^1024 chain over 16 subs) ----------
    if (w == 0) {
        float ar1k[32];
        load_row32(A1K + batch * 1024, row, ar1k);
        float S = 0.f;
#pragma unroll 1
        for (int s = 0; s < 16; s++)
            S = mv_step_rl(ar1k, S, qend_l[s][row]);
        if (lane < 32)
            qsupg[((size_t)(batch * NSUP + sup)) * 32 + row] = S;
    }
    __threadfence();
    grid.sync();

    // ---------- super-level scan (one block per batch, A^16384) ----------
    if (sup == 0 && w == 0) {
        float ark[32];
        load_row32(A16K + batch * 1024, row, ark);
        float qv[16];
#pragma unroll
        for (int s = 0; s < 16; s++)
            qv[s] = qsupg[((size_t)(batch * NSUP + s)) * 32 + row];
        float S = 0.f;
#pragma unroll 1
        for (int s = 0; s < 16; s++) {
            if (lane < 32)
                ssupg[((size_t)(batch * NSUP + s)) * 32 + row] = S;
            S = mv_step_rl(ark, S, qv[s]);
        }
    }
    __threadfence();
    grid.sync();

    // ---------- seeded sub starts (wave 0, block-local) ----------
    if (w == 0) {
        float ar1k[32];
        load_row32(A1K + batch * 1024, row, ar1k);
        float Sq = ssupg[((size_t)(batch * NSUP + sup)) * 32 + row];
#pragma unroll 1
        for (int j = 0; j < 16; j++) {
            if (lane < 32) ssub_l[j][row] = Sq;
            Sq = mv_step_rl(ar1k, Sq, qend_l[j][row]);
        }
    }
    __syncthreads();

    // ---------- seeded chunk scan: overwrite plds with chunk START states ----
    {
        float ar[32];
        load_row32(A64 + batch * 1024, row, ar);
        float q0 = ssub_l[w * 4 + 0][row];
        float q1 = ssub_l[w * 4 + 1][row];
        float q2 = ssub_l[w * 4 + 2][row];
        float q3 = ssub_l[w * 4 + 3][row];
#pragma unroll 1
        for (int j = 0; j < SUB; j++) {
            float p0 = plds[w][0 * SUB + j][row];
            float p1 = plds[w][1 * SUB + j][row];
            float p2 = plds[w][2 * SUB + j][row];
            float p3 = plds[w][3 * SUB + j][row];
            if (lane < 32) {
                plds[w][0 * SUB + j][row] = q0;
                plds[w][1 * SUB + j][row] = q1;
                plds[w][2 * SUB + j][row] = q2;
                plds[w][3 * SUB + j][row] = q3;
            }
            q0 = mv_step_rl(ar, q0, p0);
            q1 = mv_step_rl(ar, q1, p1);
            q2 = mv_step_rl(ar, q2, p2);
            q3 = mv_step_rl(ar, q3, p3);
        }
    }
    __syncthreads();

    // ---------- phase 2: corrected-init biquad pass, write output ----------
#pragma unroll
    for (int i = 0; i < NB; i++) {
        s1[i] = plds[w][lane][2 * i];
        s2[i] = plds[w][lane][2 * i + 1];
    }
    {
        float4* ogv = (float4*)(out + (size_t)batch * T_LEN
                                + ((size_t)grp * GRP + lane) * L);
        float4 xv = xgv[0];
#pragma unroll 1
        for (int tt = 0; tt < 15; tt++) {
            float4 xc = xv;
            xv = xgv[tt + 1];
            biquad4(xc, ing, c0, c1, c2, c3, c4, s1, s2, ys);
            float4 yv; yv.x = outg * ys[0]; yv.y = outg * ys[1];
            yv.z = outg * ys[2]; yv.w = outg * ys[3];
            ogv[tt] = yv;
        }
        biquad4(xv, ing, c0, c1, c2, c3, c4, s1, s2, ys);
        float4 yv; yv.x = outg * ys[0]; yv.y = outg * ys[1];
        yv.z = outg * ys[2]; yv.w = outg * ys[3];
        ogv[15] = yv;
    }
}

// ---------------- launcher ----------------
extern "C" void kernel_launch(void* const* d_in, const int* in_sizes, int n_in,
                              void* d_out, int out_size, void* d_ws, size_t ws_size,
                              hipStream_t stream) {
    const float* audio  = (const float*)d_in[0];
    const float* params = (const float*)d_in[1];
    float* out = (float*)d_out;
    float* ws  = (float*)d_ws;

    float* coefs = ws + OFF_COEF;
    float* A64   = ws + OFF_A64;
    float* A1K   = ws + OFF_A1K;
    float* A16K  = ws + OFF_A16K;
    float* qsupg = ws + OFF_QSUP;
    float* ssupg = ws + OFF_SSUP;

    k0_setup<<<BATCH, 256, 0, stream>>>(params, coefs, A64, A1K, A16K);

    void* kargs[] = {(void*)&audio, (void*)&coefs, (void*)&A64, (void*)&A1K,
                     (void*)&A16K, (void*)&qsupg, (void*)&ssupg, (void*)&out};
    hipLaunchCooperativeKernel((const void*)kfused, dim3(256), dim3(256),
                               kargs, 0, stream);
}